// Round 13
// baseline (231.788 us; speedup 1.0000x reference)
//
#include <hip/hip_runtime.h>
#include <cstdint>

// MXFP4 fake-quant linear: out = qdq(A) @ qdq(W)^T + bias
// Stage 1: quantize fp32 -> packed e2m1 + e8m0 scales, interleaved-8 scale
//          layout sc[(kb/8)][row][kb%8] (one 8B load = 8 k-blocks of a row).
// Stage 2: fp4 GEMM, 256x256 tile, BK=256 (4 k-steps of 32x32x64), 512 thr
//          = 8 waves (2M x 4N), dbuf 128 KB LDS, 1 WG/CU, grid 256
//          (XCD-bijective), v8 counted-vmcnt skeleton.
// v10 = v9 minus the spill: per-ks fragment reads (no ks double-buffer,
// -48 regs) => ~200 VGPR total, fits the 256 cap of launch_bounds(512,2).
// (v9 spilled: WRITE_SIZE 175 MB vs C=64 MB, GEMM 69us.)

#define BM 256
#define BN 256
#define BK 256      // K elements per sync iteration = 4 k-steps of 64

typedef float floatx16 __attribute__((ext_vector_type(16)));
typedef int intx8 __attribute__((ext_vector_type(8)));

#define GLOBAL_AS __attribute__((address_space(1)))
#define LDS_AS __attribute__((address_space(3)))

// ---------------- quantize fp32 -> packed fp4 + e8m0 scales ----------------

__device__ __forceinline__ int enc1(float x, float inv) {
    float q = x * inv;                         // inv = 2^-(e-2), exact
    q = fminf(fmaxf(q, -6.0f), 6.0f);
    int s = (int)(__float_as_uint(q) >> 31) << 3;
    float aq = fabsf(q);
    float ilsb = aq < 2.0f ? 2.0f : (aq < 4.0f ? 1.0f : 0.5f);
    float lsb  = aq < 2.0f ? 0.5f : (aq < 4.0f ? 1.0f : 2.0f);
    float ar = rintf(aq * ilsb) * lsb;         // RNE onto e2m1 grid
    int c;
    if (ar < 2.0f)      c = (int)(ar * 2.0f);  // 0,.5,1,1.5 -> 0..3
    else if (ar < 4.0f) c = 2 + (int)ar;       // 2,3 -> 4,5
    else                c = 4 + (int)(ar * 0.5f); // 4,6 -> 6,7
    return c | s;
}

__global__ void quant_mxfp4_v5(const float* __restrict__ A, uint8_t* __restrict__ Aq,
                               uint8_t* __restrict__ Asc,
                               const float* __restrict__ W, uint8_t* __restrict__ Wq,
                               uint8_t* __restrict__ Wsc,
                               long na4, long ntot4, int s4, long Mr, long Nr) {
    long t = (long)blockIdx.x * 256 + threadIdx.x;
    if (t >= ntot4) return;
    const float* src; uint8_t* dq; uint8_t* ds; long idx; long rows;
    if (t < na4) { src = A; dq = Aq; ds = Asc; idx = t; rows = Mr; }
    else         { src = W; dq = Wq; ds = Wsc; idx = t - na4; rows = Nr; }

    float4 f = ((const float4*)src)[idx];
    float amax = fmaxf(fmaxf(fabsf(f.x), fabsf(f.y)),
                       fmaxf(fabsf(f.z), fabsf(f.w)));
    amax = fmaxf(amax, __shfl_xor(amax, 1));
    amax = fmaxf(amax, __shfl_xor(amax, 2));
    amax = fmaxf(amax, __shfl_xor(amax, 4));

    int ebits = (int)((__float_as_uint(amax) >> 23) & 0xff);
    int sb;
    float inv;
    if (amax > 0.0f) {
        sb = ebits - 2; if (sb < 0) sb = 0;
        inv = __uint_as_float((unsigned)((256 - ebits) & 255) << 23);
    } else {
        sb = 127;              // scale 1.0, all-zero block
        inv = 0.0f;
    }

    int c0 = enc1(f.x, inv), c1 = enc1(f.y, inv);
    int c2 = enc1(f.z, inv), c3 = enc1(f.w, inv);
    ((unsigned short*)dq)[idx] =
        (unsigned short)(c0 | (c1 << 4) | (c2 << 8) | (c3 << 12));
    if ((idx & 7) == 0) {
        long m  = idx >> s4;                             // row
        int  kb = (int)((idx & ((1L << s4) - 1)) >> 3);  // k-block (32 elems)
        ds[((size_t)(kb >> 3) * rows + m) * 8 + (kb & 7)] = (uint8_t)sb;
    }
}

// ---------- fp4 GEMM: C[M,N] = (Aq,Asc) x (Wq,Wsc)^T + bias ----------
// 512 threads = 8 waves 2(M) x 4(N); per-wave 128x64 = acc[4][2] of 32x32.
// 32x32x64 frag: A row = lane&31, k-half (16B) = lane>>5.
// C/D: col = lane&31 (n), row = (reg&3)+8*(reg>>2)+4*(lane>>5) (m).
// LDS rows 128B = 8 x 16B chunks, slot c holds chunk c^(row&7) (both sides).
//
// Per iteration (buf p = t&1, scale bank CUR loaded last iteration):
//   ks0..2: 6 ds_read_b128 -> 8 MFMA (compiler lgkm waits)
//   ks3 reads -> lgkmcnt(0) -> BAR1 (buf p free)
//   sg(t+1) -> bank NXT (6 x 8B) ; stage(t+2) into p (8 DMA)
//   ks3 MFMAs ; vmcnt(8) [t+2<NT] / vmcnt(6) [else]: stage(t+1)+sg drained,
//   stage(t+2) stays in flight ; BAR2.

#define MFMAS(KS, CUR, FA, FB)                                                 \
  {                                                                            \
    int sav_[4], sbv_[2];                                                      \
    _Pragma("unroll") for (int mi = 0; mi < 4; ++mi)                           \
      sav_[mi] = (int)((((KS) < 2) ? (sgA[CUR][mi].x >> (((KS)*2 + q2)*8))     \
                  : (sgA[CUR][mi].y >> ((((KS)-2)*2 + q2)*8))) & 0xffu);       \
    _Pragma("unroll") for (int ni = 0; ni < 2; ++ni)                           \
      sbv_[ni] = (int)((((KS) < 2) ? (sgB[CUR][ni].x >> (((KS)*2 + q2)*8))     \
                  : (sgB[CUR][ni].y >> ((((KS)-2)*2 + q2)*8))) & 0xffu);       \
    intx8 b80_, b81_;                                                          \
    b80_[0] = FB[0].x; b80_[1] = FB[0].y; b80_[2] = FB[0].z;                   \
    b80_[3] = FB[0].w; b80_[4] = 0; b80_[5] = 0; b80_[6] = 0; b80_[7] = 0;     \
    b81_[0] = FB[1].x; b81_[1] = FB[1].y; b81_[2] = FB[1].z;                   \
    b81_[3] = FB[1].w; b81_[4] = 0; b81_[5] = 0; b81_[6] = 0; b81_[7] = 0;     \
    __builtin_amdgcn_s_setprio(1);                                             \
    _Pragma("unroll") for (int mi = 0; mi < 4; ++mi) {                         \
      intx8 a8_;                                                               \
      a8_[0] = FA[mi].x; a8_[1] = FA[mi].y; a8_[2] = FA[mi].z;                 \
      a8_[3] = FA[mi].w; a8_[4] = 0; a8_[5] = 0; a8_[6] = 0; a8_[7] = 0;       \
      acc[mi][0] = __builtin_amdgcn_mfma_scale_f32_32x32x64_f8f6f4(            \
          a8_, b80_, acc[mi][0], 4, 4, 0, sav_[mi], 0, sbv_[0]);               \
      acc[mi][1] = __builtin_amdgcn_mfma_scale_f32_32x32x64_f8f6f4(            \
          a8_, b81_, acc[mi][1], 4, 4, 0, sav_[mi], 0, sbv_[1]);               \
    }                                                                          \
    __builtin_amdgcn_s_setprio(0);                                             \
  }

#define GITER(T, CUR, NXT)                                                     \
  {                                                                            \
    const int p_ = (T) & 1;                                                    \
    const uint8_t* pa_ = sA[p_];                                               \
    const uint8_t* pb_ = sB[p_];                                               \
    _Pragma("unroll") for (int ks = 0; ks < 3; ++ks) {                         \
      int4 fa_[4], fb_[2];                                                     \
      const int off_ = ((ks * 2 + q2) ^ swz) * 16;                             \
      _Pragma("unroll") for (int mi = 0; mi < 4; ++mi)                         \
        fa_[mi] = *(const int4*)(pa_ + (rA0 + mi * 32) * 128 + off_);          \
      _Pragma("unroll") for (int ni = 0; ni < 2; ++ni)                         \
        fb_[ni] = *(const int4*)(pb_ + (rB0 + ni * 32) * 128 + off_);          \
      MFMAS(ks, CUR, fa_, fb_)                                                 \
    }                                                                          \
    int4 fa3_[4], fb3_[2];                                                     \
    {                                                                          \
      const int off_ = ((6 + q2) ^ swz) * 16;                                  \
      _Pragma("unroll") for (int mi = 0; mi < 4; ++mi)                         \
        fa3_[mi] = *(const int4*)(pa_ + (rA0 + mi * 32) * 128 + off_);         \
      _Pragma("unroll") for (int ni = 0; ni < 2; ++ni)                         \
        fb3_[ni] = *(const int4*)(pb_ + (rB0 + ni * 32) * 128 + off_);         \
    }                                                                          \
    if ((T) + 1 < NT) {                                                        \
      asm volatile("s_waitcnt lgkmcnt(0)" ::: "memory");                       \
      __builtin_amdgcn_sched_barrier(0);                                       \
      __builtin_amdgcn_s_barrier(); /* BAR1: buf p free for overwrite */       \
      _Pragma("unroll") for (int mi = 0; mi < 4; ++mi)                         \
        sgA[NXT][mi] = *(const uint2*)(Asc +                                   \
            ((size_t)((T) + 1) * M + m0 + rA0 + mi * 32) * 8);                 \
      _Pragma("unroll") for (int ni = 0; ni < 2; ++ni)                         \
        sgB[NXT][ni] = *(const uint2*)(Wsc +                                   \
            ((size_t)((T) + 1) * N + n0 + rB0 + ni * 32) * 8);                 \
      __builtin_amdgcn_sched_barrier(0);                                       \
      if ((T) + 2 < NT) stage((T) + 2);                                        \
      __builtin_amdgcn_sched_barrier(0);                                       \
    }                                                                          \
    MFMAS(3, CUR, fa3_, fb3_)                                                  \
    if ((T) + 1 < NT) {                                                        \
      if ((T) + 2 < NT) asm volatile("s_waitcnt vmcnt(8)" ::: "memory");       \
      else              asm volatile("s_waitcnt vmcnt(6)" ::: "memory");       \
      __builtin_amdgcn_sched_barrier(0);                                       \
      __builtin_amdgcn_s_barrier(); /* BAR2: tile t+1 visible */               \
    }                                                                          \
  }

__global__ __launch_bounds__(512, 2) void gemm_fp4_v10(
        const uint8_t* __restrict__ Aq, const uint8_t* __restrict__ Asc,
        const uint8_t* __restrict__ Wq, const uint8_t* __restrict__ Wsc,
        const float* __restrict__ bias, float* __restrict__ C,
        int M, int N, int K) {
    __shared__ __align__(16) uint8_t sA[2][BM * 128];  // 2 x 32 KB
    __shared__ __align__(16) uint8_t sB[2][BN * 128];  // 2 x 32 KB

    const int tid = threadIdx.x;
    const int lane = tid & 63;
    const int w = tid >> 6;          // 0..7
    const int wr = w >> 2;           // 0..1 (M): rows wr*128
    const int wc = w & 3;            // 0..3 (N): cols wc*64
    const int row32 = lane & 31;
    const int q2 = lane >> 5;        // k-half within a 64-K step

    // XCD-bijective remap: grid 256 (id%8 = XCD); per-XCD set = 4 A-panels
    // (1 MB) + all 8 B-panels (2.1 MB) = 3.1 MB < 4 MB L2.
    const int id = blockIdx.x;
    const int g = id & 7, h = id >> 3;   // h 0..31
    const int by = g * 4 + (h & 3);      // 0..31
    const int bx = h >> 2;               // 0..7
    const int m0 = by * BM;
    const int n0 = bx * BN;
    const int KB2 = K >> 1;
    const int NT = K / BK;               // 8 (even)

    const int rA0 = wr * 128 + row32;    // A row within tile
    const int rB0 = wc * 64 + row32;     // B row within tile
    const int swz = row32 & 7;

    floatx16 acc[4][2];
#pragma unroll
    for (int i = 0; i < 4; i++)
#pragma unroll
        for (int j = 0; j < 2; j++)
#pragma unroll
            for (int r = 0; r < 16; r++) acc[i][j][r] = 0.f;

    // 8 uniform DMA insts/thread/iter: 4 A + 4 B (16B each), 64 KB total
    auto stage = [&](int tt) {
        const int bb = tt & 1;
        const int kb = tt * 128;             // bytes along packed K
#pragma unroll
        for (int it = 0; it < 4; ++it) {
            int idx = it * 512 + tid;        // 0..2047 16B chunks
            int row = idx >> 3, c = idx & 7;
            int gc = c ^ (row & 7);          // pre-swizzled source chunk
            const uint8_t* src = Aq + (size_t)(m0 + row) * KB2 + kb + gc * 16;
            __builtin_amdgcn_global_load_lds((GLOBAL_AS void*)src,
                (LDS_AS void*)(&sA[bb][idx * 16]), 16, 0, 0);
        }
#pragma unroll
        for (int it = 0; it < 4; ++it) {
            int idx = it * 512 + tid;
            int row = idx >> 3, c = idx & 7;
            int gc = c ^ (row & 7);
            const uint8_t* src = Wq + (size_t)(n0 + row) * KB2 + kb + gc * 16;
            __builtin_amdgcn_global_load_lds((GLOBAL_AS void*)src,
                (LDS_AS void*)(&sB[bb][idx * 16]), 16, 0, 0);
        }
    };

    uint2 sgA[2][4], sgB[2][2];          // scale banks, static indices only

    // ---- prologue: stage(0), sg(0), stage(1); vmcnt(8) leaves stage(1) ----
    stage(0);
    __builtin_amdgcn_sched_barrier(0);
#pragma unroll
    for (int mi = 0; mi < 4; ++mi)
        sgA[0][mi] = *(const uint2*)(Asc + ((size_t)m0 + rA0 + mi * 32) * 8);
#pragma unroll
    for (int ni = 0; ni < 2; ++ni)
        sgB[0][ni] = *(const uint2*)(Wsc + ((size_t)n0 + rB0 + ni * 32) * 8);
    __builtin_amdgcn_sched_barrier(0);
    stage(1);
    __builtin_amdgcn_sched_barrier(0);
    asm volatile("s_waitcnt vmcnt(8)" ::: "memory");
    __builtin_amdgcn_sched_barrier(0);
    __builtin_amdgcn_s_barrier();

    for (int t = 0; t < NT; t += 2) {
        GITER(t, 0, 1);
        GITER(t + 1, 1, 0);
    }

    // ---- epilogue: col = lane&31 (n), row = (r&3)+8*(r>>2)+4*q2 (m) ----
#pragma unroll
    for (int ni = 0; ni < 2; ++ni) {
        int n = n0 + wc * 64 + ni * 32 + row32;
        float bv = bias[n];
#pragma unroll
        for (int mi = 0; mi < 4; ++mi) {
            int mb = m0 + wr * 128 + mi * 32 + 4 * q2;
#pragma unroll
            for (int r = 0; r < 16; ++r) {
                int m = mb + (r & 3) + 8 * (r >> 2);
                C[(size_t)m * N + n] = acc[mi][ni][r] + bv;
            }
        }
    }
}

// ---------------- launch ----------------

extern "C" void kernel_launch(void* const* d_in, const int* in_sizes, int n_in,
                              void* d_out, int out_size, void* d_ws, size_t ws_size,
                              hipStream_t stream) {
    const float* inp  = (const float*)d_in[0];
    const float* wgt  = (const float*)d_in[1];
    const float* bias = (const float*)d_in[2];
    float* out = (float*)d_out;

    const int N = in_sizes[2];                 // 2048
    const int K = in_sizes[1] / N;             // 2048
    const long M = (long)in_sizes[0] / K;      // 8192

    uint8_t* Aq4 = (uint8_t*)d_ws;             // M*K/2
    uint8_t* Wq4 = Aq4 + (size_t)M * K / 2;    // N*K/2
    uint8_t* Asc = Wq4 + (size_t)N * K / 2;    // M*K/32, layout [K/256][M][8]
    uint8_t* Wsc = Asc + (size_t)M * K / 32;   // N*K/32, layout [K/256][N][8]

    int s4 = 0;
    while ((1 << s4) < (K >> 2)) ++s4;         // log2(K/4) = 9

    long na4   = (long)M * K / 4;
    long ntot4 = na4 + (long)N * K / 4;
    quant_mxfp4_v5<<<dim3((ntot4 + 255) / 256), dim3(256), 0, stream>>>(
        inp, Aq4, Asc, wgt, Wq4, Wsc, na4, ntot4, s4, M, (long)N);

    dim3 grid((N / BN) * (int)(M / BM));       // 8*32 = 256 WGs = 1/CU
    gemm_fp4_v10<<<grid, dim3(512), 0, stream>>>(
        Aq4, Asc, Wq4, Wsc, bias, out, (int)M, N, K);
}

// Round 15
// 152.688 us; speedup vs baseline: 1.5181x; 1.5181x over previous
//
#include <hip/hip_runtime.h>
#include <cstdint>

// MXFP4 fake-quant linear: out = qdq(A) @ qdq(W)^T + bias
// Stage 1: quantize fp32 -> packed e2m1 + e8m0 scales, interleaved-8 scale
//          layout sc[(kb/8)][row][kb%8] (one 8B load = 8 k-blocks of a row).
// Stage 2: fp4 GEMM in the m153-proven structure: 128x128 tile, 256 thr
//          (4 waves 2x2), BK=256 (4 k-steps of 32x32x64), double-buffered
//          64 KB LDS (2 WGs/CU), plain __syncthreads() 2-barrier loop,
//          NO manual vmcnt/sched_barrier/setprio -- compiler schedules.
//          XCD-bijective remap, XOR-swizzled LDS (both sides).
// Rationale: v8-v10 manual fencing ran 1.5-3x slower than the reference
// m153 structure (2878 TF fp4 on this FLOP count); guide m141 documents
// sched_barrier(0) order-pinning as a known ~1.7x regression. Revert to
// compiler-scheduled staging.
// (Resubmission: round-14 bench failed on GPU acquisition timeout.)

#define BM 128
#define BN 128
#define BK 256      // K elements per tile iteration = 4 k-steps of 64

typedef float floatx16 __attribute__((ext_vector_type(16)));
typedef int intx8 __attribute__((ext_vector_type(8)));

#define GLOBAL_AS __attribute__((address_space(1)))
#define LDS_AS __attribute__((address_space(3)))

// ---------------- quantize fp32 -> packed fp4 + e8m0 scales ----------------

__device__ __forceinline__ int enc1(float x, float inv) {
    float q = x * inv;                         // inv = 2^-(e-2), exact
    q = fminf(fmaxf(q, -6.0f), 6.0f);
    int s = (int)(__float_as_uint(q) >> 31) << 3;
    float aq = fabsf(q);
    float ilsb = aq < 2.0f ? 2.0f : (aq < 4.0f ? 1.0f : 0.5f);
    float lsb  = aq < 2.0f ? 0.5f : (aq < 4.0f ? 1.0f : 2.0f);
    float ar = rintf(aq * ilsb) * lsb;         // RNE onto e2m1 grid
    int c;
    if (ar < 2.0f)      c = (int)(ar * 2.0f);  // 0,.5,1,1.5 -> 0..3
    else if (ar < 4.0f) c = 2 + (int)ar;       // 2,3 -> 4,5
    else                c = 4 + (int)(ar * 0.5f); // 4,6 -> 6,7
    return c | s;
}

__global__ void quant_mxfp4_v5(const float* __restrict__ A, uint8_t* __restrict__ Aq,
                               uint8_t* __restrict__ Asc,
                               const float* __restrict__ W, uint8_t* __restrict__ Wq,
                               uint8_t* __restrict__ Wsc,
                               long na4, long ntot4, int s4, long Mr, long Nr) {
    long t = (long)blockIdx.x * 256 + threadIdx.x;
    if (t >= ntot4) return;
    const float* src; uint8_t* dq; uint8_t* ds; long idx; long rows;
    if (t < na4) { src = A; dq = Aq; ds = Asc; idx = t; rows = Mr; }
    else         { src = W; dq = Wq; ds = Wsc; idx = t - na4; rows = Nr; }

    float4 f = ((const float4*)src)[idx];
    float amax = fmaxf(fmaxf(fabsf(f.x), fabsf(f.y)),
                       fmaxf(fabsf(f.z), fabsf(f.w)));
    amax = fmaxf(amax, __shfl_xor(amax, 1));
    amax = fmaxf(amax, __shfl_xor(amax, 2));
    amax = fmaxf(amax, __shfl_xor(amax, 4));

    int ebits = (int)((__float_as_uint(amax) >> 23) & 0xff);
    int sb;
    float inv;
    if (amax > 0.0f) {
        sb = ebits - 2; if (sb < 0) sb = 0;
        inv = __uint_as_float((unsigned)((256 - ebits) & 255) << 23);
    } else {
        sb = 127;              // scale 1.0, all-zero block
        inv = 0.0f;
    }

    int c0 = enc1(f.x, inv), c1 = enc1(f.y, inv);
    int c2 = enc1(f.z, inv), c3 = enc1(f.w, inv);
    ((unsigned short*)dq)[idx] =
        (unsigned short)(c0 | (c1 << 4) | (c2 << 8) | (c3 << 12));
    if ((idx & 7) == 0) {
        long m  = idx >> s4;                             // row
        int  kb = (int)((idx & ((1L << s4) - 1)) >> 3);  // k-block (32 elems)
        ds[((size_t)(kb >> 3) * rows + m) * 8 + (kb & 7)] = (uint8_t)sb;
    }
}

// ---------- fp4 GEMM: C[M,N] = (Aq,Asc) x (Wq,Wsc)^T + bias ----------
// 256 threads = 4 waves 2(M) x 2(N); per-wave output 64x64 = acc[2][2]
// of 32x32 blocks (16 f32 each). ~64 acc regs/thread.
// 32x32x64 frag: A row = lane&31, k-half (16B = 32 elems) = lane>>5.
// C/D: col = lane&31 (n), row = (reg&3)+8*(reg>>2)+4*(lane>>5) (m).
// LDS rows 128B = 8 x 16B chunks; slot c holds global chunk c^(row&7)
// (applied on DMA source AND read side). All verified rounds 5-10.
//
// Loop (canonical m97/m153 2-barrier form, compiler-scheduled):
//   stage(0);
//   for t: __syncthreads();            // stage(t) visible (compiler drain)
//          if (t+1<NT) stage(t+1);     // DMA into other buffer
//          scales(t) -> regs; compute buf[t&1] (ds_reads + 16 MFMA);
//          __syncthreads();            // readers of buf[t&1] done

__global__ __launch_bounds__(256, 2) void gemm_fp4_v11(
        const uint8_t* __restrict__ Aq, const uint8_t* __restrict__ Asc,
        const uint8_t* __restrict__ Wq, const uint8_t* __restrict__ Wsc,
        const float* __restrict__ bias, float* __restrict__ C,
        int M, int N, int K) {
    __shared__ __align__(16) uint8_t sA[2][BM * 128];  // 2 x 16 KB
    __shared__ __align__(16) uint8_t sB[2][BN * 128];  // 2 x 16 KB

    const int tid = threadIdx.x;
    const int lane = tid & 63;
    const int w = tid >> 6;
    const int wr = w >> 1;           // 0..1 (M)
    const int wc = w & 1;            // 0..1 (N)
    const int row32 = lane & 31;
    const int q2 = lane >> 5;        // k-half within a 64-K step

    // XCD-aware bijective remap (grid 1024, id%8 = XCD): per-XCD set =
    // 8 A-panels (1 MB) + whole W (2.1 MB) = 3.1 MB < 4 MB L2.
    const int id = blockIdx.x;
    const int g = id & 7, h = id >> 3;
    const int by = g + 8 * (h & 7);  // 0..63
    const int bx = h >> 3;           // 0..15
    const int m0 = by * BM;
    const int n0 = bx * BN;
    const int KB2 = K >> 1;
    const int NT = K / BK;           // 8

    const int rA = wr * 64 + row32;  // A row within tile
    const int rB = wc * 64 + row32;  // B row within tile
    const int swz = row32 & 7;

    floatx16 acc[2][2];
#pragma unroll
    for (int i = 0; i < 2; i++)
#pragma unroll
        for (int j = 0; j < 2; j++)
#pragma unroll
            for (int r = 0; r < 16; r++) acc[i][j][r] = 0.f;

    // 8 uniform DMA insts/thread/iter: 4 A + 4 B (16B each), 32 KB total
    auto stage = [&](int tt) {
        const int bb = tt & 1;
        const int kb = tt * 128;             // bytes along packed K
#pragma unroll
        for (int it = 0; it < 4; ++it) {
            int idx = it * 256 + tid;        // 0..1023 16B chunks
            int row = idx >> 3, c = idx & 7;
            int gc = c ^ (row & 7);          // pre-swizzled source chunk
            const uint8_t* src = Aq + (size_t)(m0 + row) * KB2 + kb + gc * 16;
            __builtin_amdgcn_global_load_lds((GLOBAL_AS void*)src,
                (LDS_AS void*)(&sA[bb][idx * 16]), 16, 0, 0);
        }
#pragma unroll
        for (int it = 0; it < 4; ++it) {
            int idx = it * 256 + tid;
            int row = idx >> 3, c = idx & 7;
            int gc = c ^ (row & 7);
            const uint8_t* src = Wq + (size_t)(n0 + row) * KB2 + kb + gc * 16;
            __builtin_amdgcn_global_load_lds((GLOBAL_AS void*)src,
                (LDS_AS void*)(&sB[bb][idx * 16]), 16, 0, 0);
        }
    };

    stage(0);

    for (int t = 0; t < NT; ++t) {
        __syncthreads();                 // stage(t) landed & visible
        if (t + 1 < NT) stage(t + 1);    // prefetch into other buffer

        // scales for tile t: one 8B load per 32-row block (interleaved-8)
        uint2 sga[2], sgb[2];
#pragma unroll
        for (int mi = 0; mi < 2; ++mi)
            sga[mi] = *(const uint2*)(Asc + ((size_t)t * M + m0 + rA + mi * 32) * 8);
#pragma unroll
        for (int ni = 0; ni < 2; ++ni)
            sgb[ni] = *(const uint2*)(Wsc + ((size_t)t * N + n0 + rB + ni * 32) * 8);

        const uint8_t* pa = sA[t & 1];
        const uint8_t* pb = sB[t & 1];

#pragma unroll
        for (int ks = 0; ks < 4; ++ks) {
            const int off = ((ks * 2 + q2) ^ swz) * 16;
            int4 fa0 = *(const int4*)(pa + (rA)      * 128 + off);
            int4 fa1 = *(const int4*)(pa + (rA + 32) * 128 + off);
            int4 fb0 = *(const int4*)(pb + (rB)      * 128 + off);
            int4 fb1 = *(const int4*)(pb + (rB + 32) * 128 + off);

            int sa0, sa1, sb0, sb1;
            if (ks < 2) {
                sa0 = (int)((sga[0].x >> ((ks * 2 + q2) * 8)) & 0xffu);
                sa1 = (int)((sga[1].x >> ((ks * 2 + q2) * 8)) & 0xffu);
                sb0 = (int)((sgb[0].x >> ((ks * 2 + q2) * 8)) & 0xffu);
                sb1 = (int)((sgb[1].x >> ((ks * 2 + q2) * 8)) & 0xffu);
            } else {
                sa0 = (int)((sga[0].y >> (((ks - 2) * 2 + q2) * 8)) & 0xffu);
                sa1 = (int)((sga[1].y >> (((ks - 2) * 2 + q2) * 8)) & 0xffu);
                sb0 = (int)((sgb[0].y >> (((ks - 2) * 2 + q2) * 8)) & 0xffu);
                sb1 = (int)((sgb[1].y >> (((ks - 2) * 2 + q2) * 8)) & 0xffu);
            }

            intx8 a0, a1, b0, b1;
            a0[0] = fa0.x; a0[1] = fa0.y; a0[2] = fa0.z; a0[3] = fa0.w;
            a1[0] = fa1.x; a1[1] = fa1.y; a1[2] = fa1.z; a1[3] = fa1.w;
            b0[0] = fb0.x; b0[1] = fb0.y; b0[2] = fb0.z; b0[3] = fb0.w;
            b1[0] = fb1.x; b1[1] = fb1.y; b1[2] = fb1.z; b1[3] = fb1.w;
#pragma unroll
            for (int z = 4; z < 8; ++z) { a0[z] = 0; a1[z] = 0; b0[z] = 0; b1[z] = 0; }

            acc[0][0] = __builtin_amdgcn_mfma_scale_f32_32x32x64_f8f6f4(
                a0, b0, acc[0][0], 4, 4, 0, sa0, 0, sb0);
            acc[0][1] = __builtin_amdgcn_mfma_scale_f32_32x32x64_f8f6f4(
                a0, b1, acc[0][1], 4, 4, 0, sa0, 0, sb1);
            acc[1][0] = __builtin_amdgcn_mfma_scale_f32_32x32x64_f8f6f4(
                a1, b0, acc[1][0], 4, 4, 0, sa1, 0, sb0);
            acc[1][1] = __builtin_amdgcn_mfma_scale_f32_32x32x64_f8f6f4(
                a1, b1, acc[1][1], 4, 4, 0, sa1, 0, sb1);
        }

        __syncthreads();                 // readers of buf[t&1] done
    }

    // ---- epilogue: col = lane&31 (n), row = (r&3)+8*(r>>2)+4*q2 (m) ----
#pragma unroll
    for (int j = 0; j < 2; ++j) {
        int n = n0 + wc * 64 + j * 32 + row32;
        float bv = bias[n];
#pragma unroll
        for (int i = 0; i < 2; ++i) {
            int mb = m0 + wr * 64 + i * 32 + 4 * q2;
#pragma unroll
            for (int r = 0; r < 16; ++r) {
                int m = mb + (r & 3) + 8 * (r >> 2);
                C[(size_t)m * N + n] = acc[i][j][r] + bv;
            }
        }
    }
}

// ---------------- launch ----------------

extern "C" void kernel_launch(void* const* d_in, const int* in_sizes, int n_in,
                              void* d_out, int out_size, void* d_ws, size_t ws_size,
                              hipStream_t stream) {
    const float* inp  = (const float*)d_in[0];
    const float* wgt  = (const float*)d_in[1];
    const float* bias = (const float*)d_in[2];
    float* out = (float*)d_out;

    const int N = in_sizes[2];                 // 2048
    const int K = in_sizes[1] / N;             // 2048
    const long M = (long)in_sizes[0] / K;      // 8192

    uint8_t* Aq4 = (uint8_t*)d_ws;             // M*K/2
    uint8_t* Wq4 = Aq4 + (size_t)M * K / 2;    // N*K/2
    uint8_t* Asc = Wq4 + (size_t)N * K / 2;    // M*K/32, layout [K/256][M][8]
    uint8_t* Wsc = Asc + (size_t)M * K / 32;   // N*K/32, layout [K/256][N][8]

    int s4 = 0;
    while ((1 << s4) < (K >> 2)) ++s4;         // log2(K/4) = 9

    long na4   = (long)M * K / 4;
    long ntot4 = na4 + (long)N * K / 4;
    quant_mxfp4_v5<<<dim3((ntot4 + 255) / 256), dim3(256), 0, stream>>>(
        inp, Aq4, Asc, wgt, Wq4, Wsc, na4, ntot4, s4, M, (long)N);

    dim3 grid((N / BN) * (int)(M / BM));       // 16*64 = 1024, 2 resident/CU
    gemm_fp4_v11<<<grid, dim3(256), 0, stream>>>(
        Aq4, Asc, Wq4, Wsc, bias, out, (int)M, N, K);
}